// Round 10
// baseline (377.588 us; speedup 1.0000x reference)
//
#include <hip/hip_runtime.h>

#define NB 8
#define NC 64
#define NH 256
#define NW 256

typedef short s16x8 __attribute__((ext_vector_type(8)));
typedef float f32x16 __attribute__((ext_vector_type(16)));

static __device__ __forceinline__ unsigned short f2bf(float f) {
  unsigned int u = __float_as_uint(f);
  unsigned int r = (u + 0x7fffu + ((u >> 16) & 1u)) >> 16;
  return (unsigned short)r;
}

// ---------------- fast path ----------------
// ws layout (bytes):
//   Wf  [ck][s(10)][m(2)][lane(64)][8ci] bf16 : 0 .. 81920  (fragment-ordered)
//   bias[64] f32                              : 81920 .. 82176
#define WS_NEEDED 82176ull

static __device__ __forceinline__ int wfoff(int tap, int co, int ci) {
  // fragment order: [ck][tap][m][lane][j]; lane = (cihi<<5)|(co&31), j = ci&7
  int ck = ci >> 4;
  int lane = (((ci >> 3) & 1) << 5) | (co & 31);
  int m = co >> 5;
  return ((((ck * 10 + tap) * 2 + m) * 64 + lane) << 3) | (ci & 7);
}

// Parallel prep: blocks 0..15 = M-fold (tap 9), block 16 = bias,
// blocks 16..63 = conv-weight bf16 transpose. All writes fragment-ordered.
__global__ __launch_bounds__(256) void prep_fast(
    const float* __restrict__ lw, const float* __restrict__ lb,
    const float* __restrict__ w2a_w, const float* __restrict__ w2a_b,
    const float* __restrict__ w2b_w, const float* __restrict__ w2b_b,
    unsigned short* __restrict__ Wf, float* __restrict__ bias) {
  int blk = blockIdx.x;
  int t = threadIdx.x;
  if (blk < 16) {
    // M[co][ci] = sum_q sum_c w2b_w[q][co][c] * w2a_w[q][c][ci], scaled 1/90
    int gidx = blk * 256 + t;
    int ci = gidx & 63, co = gidx >> 6;
    float acc = 0.f;
    for (int q = 0; q < 4; ++q) {
      const float* wb = w2b_w + (q * 64 + co) * 64;
      const float* wa = w2a_w + q * 4096 + ci;
      for (int c = 0; c < 64; ++c) acc += wb[c] * wa[c * 64];
    }
    Wf[wfoff(9, co, ci)] = f2bf(acc * (1.0f / 90.0f));
    return;
  }
  for (int idx = (blk - 16) * 256 + t; idx < 64 * 64 * 9; idx += 48 * 256) {
    int ci = idx & 63;
    int co = (idx >> 6) & 63;
    int tap = idx >> 12;
    Wf[wfoff(tap, co, ci)] = f2bf(lw[(co * 64 + ci) * 9 + tap]);
  }
  if (blk == 16 && t < 64) {
    float acc = lb[t];
    for (int q = 0; q < 4; ++q) {
      const float* wb = w2b_w + (q * 64 + t) * 64;
      const float* ba = w2a_b + q * 64;
      for (int c = 0; c < 64; ++c) acc += wb[c] * ba[c];
      acc += w2b_b[q * 64 + t];
    }
    bias[t] = acc;
  }
}

// Fused stage2: per ci-chunk {stage f32 circular tile -> barrier ->
// convert (bf16 zero-pad conv tile) + Sn (from f32 circ) + weight copy ->
// barrier -> 10 MFMA K-steps}. D[co][px] = sum_k Wf[k][co] * B[k][px].
// LDS regions:
#define XF_OFF 0                 // f32 circ tile [16ci][6h][68w pad] = 26112 B
#define XH_OFF 26112             // bf16 zero tile: 396 rows (6h x 66w) x 48B = 19008
#define SN_OFF 45120             // bf16 Sn: 256 rows (4h x 64w) x 48B = 12288
#define WL_OFF 57408             // weights: 1280 chunks x 16B = 20480
#define LDS_SZ 77888

__global__ __launch_bounds__(256, 2) void stage2(
    const float* __restrict__ x, const unsigned short* __restrict__ Wf,
    const float* __restrict__ bias, float* __restrict__ out) {
  __shared__ __align__(16) char smem[LDS_SZ];
  int id = blockIdx.x;
  int bid = (id & 7) * 256 + (id >> 3);   // XCD-contiguous chunks
  int b = bid >> 8;
  int rem = bid & 255;
  int h0 = (rem >> 2) * 4, w0 = (rem & 3) * 64;
  int tid = threadIdx.x;
  int lane = tid & 63, wv = tid >> 6;
  int l31 = lane & 31, g = lane >> 5;

  f32x16 acc[2][2];
#pragma unroll
  for (int m = 0; m < 2; ++m)
#pragma unroll
    for (int n = 0; n < 2; ++n)
#pragma unroll
      for (int i = 0; i < 16; ++i) acc[m][n][i] = 0.f;

  for (int ck = 0; ck < 4; ++ck) {
    int ci0 = ck * 16;
    // ---- A: stage f32 circular tile (16 ci x 6 h x 66 w), dense row reads ----
    // (writes XF only; prev-chunk MFMA reads XH/SN/WL -> no hazard, no barrier)
    for (int idx = tid; idx < 6336; idx += 256) {
      int wc = idx % 66;
      int t2 = idx / 66;      // 0..95
      int hr = t2 % 6;
      int ci = t2 / 6;
      int gh = (h0 - 1 + hr) & 255;
      int gw = (w0 - 1 + wc) & 255;
      float v = x[(((size_t)b * 64 + ci0 + ci) * 256 + gh) * 256 + gw];
      *(float*)(smem + XF_OFF + ((ci * 6 + hr) * 68 + wc) * 4) = v;
    }
    __syncthreads();   // B1: XF ready; also guarantees all waves finished prev MFMA
    // ---- C1: zero-padded bf16 conv tile (792 x 16B chunks) ----
    for (int idx = tid; idx < 792; idx += 256) {
      int row = idx >> 1, half = idx & 1;
      int hr = row / 66, wc = row - hr * 66;
      int gh = h0 - 1 + hr, gw = w0 - 1 + wc;
      uint4 pk = make_uint4(0u, 0u, 0u, 0u);
      if ((unsigned)gh < 256u && (unsigned)gw < 256u) {
        const char* base = smem + XF_OFF + (hr * 68 + wc) * 4;
        unsigned int* pp = (unsigned int*)&pk;
#pragma unroll
        for (int j = 0; j < 4; ++j) {
          int cl = half * 8 + 2 * j;
          float lo = *(const float*)(base + (cl) * 6 * 68 * 4);
          float hi = *(const float*)(base + (cl + 1) * 6 * 68 * 4);
          pp[j] = (unsigned int)f2bf(lo) | ((unsigned int)f2bf(hi) << 16);
        }
      }
      *(uint4*)(smem + XH_OFF + row * 48 + half * 16) = pk;
    }
    // ---- C2: Sn = u^2 + v from f32 circular tile (512 x 16B chunks) ----
    for (int idx = tid; idx < 512; idx += 256) {
      int row = idx >> 1, half = idx & 1;
      int ph = row >> 6, pw = row & 63;
      uint4 pk;
      unsigned int* pp = (unsigned int*)&pk;
#pragma unroll
      for (int j = 0; j < 4; ++j) {
        unsigned int two = 0;
#pragma unroll
        for (int e = 0; e < 2; ++e) {
          int cl = half * 8 + 2 * j + e;
          const float* p = (const float*)(smem + XF_OFF) + (cl * 6 + ph) * 68 + pw;
          float u = p[0] + p[1] + p[2] + p[68] + p[69] + p[70] +
                    p[136] + p[137] + p[138];
          float v = p[0]*p[0] + p[1]*p[1] + p[2]*p[2] +
                    p[68]*p[68] + p[69]*p[69] + p[70]*p[70] +
                    p[136]*p[136] + p[137]*p[137] + p[138]*p[138];
          float sn = u * u + v;
          two |= ((unsigned int)f2bf(sn)) << (16 * e);
        }
        pp[j] = two;
      }
      *(uint4*)(smem + SN_OFF + row * 48 + half * 16) = pk;
    }
    // ---- C3: weights, contiguous 20 KB copy (L2-resident) ----
    {
      const char* wsrc = (const char*)Wf + ck * 20480;
      for (int idx = tid; idx < 1280; idx += 256) {
        float4 v = *(const float4*)(wsrc + idx * 16);
        *(float4*)(smem + WL_OFF + idx * 16) = v;
      }
    }
    __syncthreads();   // B2: XH/SN/WL ready

    // ---- E: 10 K-steps (taps 0..8 conv, tap 9 = Sn) ----
#pragma unroll
    for (int s = 0; s < 10; ++s) {
      s16x8 af[2], bf[2];
#pragma unroll
      for (int m = 0; m < 2; ++m)
        af[m] = *(const s16x8*)(smem + WL_OFF + ((s * 2 + m) * 64 + lane) * 16);
      if (s < 9) {
        const int dy = s / 3, dx = s - dy * 3;
        int rbase = ((wv + dy) * 66 + l31 + dx) * 48 + g * 16;
#pragma unroll
        for (int n = 0; n < 2; ++n)
          bf[n] = *(const s16x8*)(smem + XH_OFF + rbase + n * 32 * 48);
      } else {
        int rbase = (wv * 64 + l31) * 48 + g * 16;
#pragma unroll
        for (int n = 0; n < 2; ++n)
          bf[n] = *(const s16x8*)(smem + SN_OFF + rbase + n * 32 * 48);
      }
#pragma unroll
      for (int m = 0; m < 2; ++m)
#pragma unroll
        for (int n = 0; n < 2; ++n)
          acc[m][n] = __builtin_amdgcn_mfma_f32_32x32x16_bf16(af[m], bf[n],
                                                              acc[m][n], 0, 0, 0);
    }
  }

  // ---- epilogue: D row = (reg&3) + 8*(reg>>2) + 4*(lane>>5), col = lane&31 ----
  int h = h0 + wv;
#pragma unroll
  for (int m = 0; m < 2; ++m) {
#pragma unroll
    for (int reg = 0; reg < 16; ++reg) {
      int co = m * 32 + (reg & 3) + 8 * (reg >> 2) + 4 * (lane >> 5);
      float bv = bias[co];
#pragma unroll
      for (int n = 0; n < 2; ++n) {
        int w = w0 + n * 32 + l31;
        out[(((size_t)b * 64 + co) * 256 + h) * 256 + w] = acc[m][n][reg] + bv;
      }
    }
  }
}

// ---------------- fallback path (verified round-2 fp32 kernel) ----------------
#define TW 128
#define CC 16

__global__ __launch_bounds__(256) void prep_kernel(
    const float* __restrict__ lw, const float* __restrict__ w2a_w,
    const float* __restrict__ w2a_b, const float* __restrict__ w2b_w,
    const float* __restrict__ w2b_b, float* __restrict__ Mt,
    float* __restrict__ bias2, float* __restrict__ Wt) {
  int t = threadIdx.x;
  for (int idx = t; idx < NC * NC; idx += 256) {
    int i = idx >> 6, o = idx & 63;
    float acc = 0.f;
    for (int q = 0; q < 4; ++q) {
      const float* wb = w2b_w + (q * NC + o) * NC;
      const float* wa = w2a_w + q * NC * NC + i;
      for (int c = 0; c < NC; ++c) acc += wb[c] * wa[c * NC];
    }
    Mt[idx] = acc;
  }
  if (t < NC) {
    float acc = 0.f;
    for (int q = 0; q < 4; ++q) {
      const float* wb = w2b_w + (q * NC + t) * NC;
      const float* ba = w2a_b + q * NC;
      for (int c = 0; c < NC; ++c) acc += wb[c] * ba[c];
      acc += w2b_b[q * NC + t];
    }
    bias2[t] = acc;
  }
  for (int idx = t; idx < NC * 9 * NC; idx += 256) {
    int co = idx & 63;
    int tap = (idx >> 6) % 9;
    int ci = idx / (9 * 64);
    Wt[idx] = lw[(co * NC + ci) * 9 + tap];
  }
}

__global__ __launch_bounds__(256) void volterra_main(
    const float* __restrict__ x, const float* __restrict__ lb,
    const float* __restrict__ Mt, const float* __restrict__ bias2,
    const float* __restrict__ Wt, float* __restrict__ out) {
  __shared__ __align__(16) float xt[CC][3][TW + 8];
  __shared__ __align__(16) float snt[CC][TW];
  const int tid = threadIdx.x;
  const int wc = blockIdx.x;
  const int h = blockIdx.y;
  const int b = blockIdx.z;
  const int w0 = wc * TW;
  const int co = tid >> 2;
  const int wq = tid & 3;
  const int wl0 = wq * 32;
  const bool fix_lo = (w0 == 0) && (wq == 0);
  const bool fix_hi = (w0 + TW == NW) && (wq == 3);
  float acc[32];
  {
    float base = lb[co] + bias2[co];
#pragma unroll
    for (int k = 0; k < 32; ++k) acc[k] = base;
  }
  for (int cc = 0; cc < NC / CC; ++cc) {
    const int ci0 = cc * CC;
    __syncthreads();
    for (int idx = tid; idx < CC * 3 * (TW + 2); idx += 256) {
      int col = idx % (TW + 2);
      int rem = idx / (TW + 2);
      int dy = rem % 3;
      int ci = rem / 3;
      int gr = (h + dy - 1 + NH) & (NH - 1);
      int gc = (w0 - 1 + col + NW) & (NW - 1);
      xt[ci][dy][col] = x[(((size_t)b * NC + ci0 + ci) * NH + gr) * NW + gc];
    }
    __syncthreads();
    for (int idx = tid; idx < CC * TW; idx += 256) {
      int ci = idx >> 7, wl = idx & (TW - 1);
      float s1 = 0.f, s2 = 0.f;
#pragma unroll
      for (int dy = 0; dy < 3; ++dy)
#pragma unroll
        for (int dx = 0; dx < 3; ++dx) {
          float v = xt[ci][dy][wl + dx];
          s1 += v;
          s2 += v * v;
        }
      snt[ci][wl] = (s1 * s1 + s2) * (0.5f / 45.0f);
    }
    __syncthreads();
    for (int ci = 0; ci < CC; ++ci) {
      const int cig = ci0 + ci;
      {
        float m = Mt[cig * NC + co];
        const float4* sp = reinterpret_cast<const float4*>(&snt[ci][wl0]);
#pragma unroll
        for (int j = 0; j < 8; ++j) {
          float4 v = sp[j];
          acc[4 * j + 0] += m * v.x;
          acc[4 * j + 1] += m * v.y;
          acc[4 * j + 2] += m * v.z;
          acc[4 * j + 3] += m * v.w;
        }
      }
      const float* wtp = Wt + cig * 9 * NC + co;
#pragma unroll
      for (int dy = 0; dy < 3; ++dy) {
        if (dy == 0 && h == 0) continue;
        if (dy == 2 && h == NH - 1) continue;
        float wv0 = wtp[(dy * 3 + 0) * NC];
        float wv1 = wtp[(dy * 3 + 1) * NC];
        float wv2 = wtp[(dy * 3 + 2) * NC];
        float xr[34];
        const float4* rp = reinterpret_cast<const float4*>(&xt[ci][dy][wl0]);
#pragma unroll
        for (int j = 0; j < 8; ++j) {
          float4 v = rp[j];
          xr[4 * j + 0] = v.x;
          xr[4 * j + 1] = v.y;
          xr[4 * j + 2] = v.z;
          xr[4 * j + 3] = v.w;
        }
        xr[32] = xt[ci][dy][wl0 + 32];
        xr[33] = xt[ci][dy][wl0 + 33];
        if (fix_lo) xr[0] = 0.f;
        if (fix_hi) xr[33] = 0.f;
#pragma unroll
        for (int k = 0; k < 32; ++k) {
          acc[k] += wv0 * xr[k] + wv1 * xr[k + 1] + wv2 * xr[k + 2];
        }
      }
    }
  }
  float* op = out + (((size_t)b * NC + co) * NH + h) * NW + w0 + wl0;
#pragma unroll
  for (int j = 0; j < 8; ++j) {
    float4 v;
    v.x = acc[4 * j + 0];
    v.y = acc[4 * j + 1];
    v.z = acc[4 * j + 2];
    v.w = acc[4 * j + 3];
    reinterpret_cast<float4*>(op)[j] = v;
  }
}

extern "C" void kernel_launch(void* const* d_in, const int* in_sizes, int n_in,
                              void* d_out, int out_size, void* d_ws, size_t ws_size,
                              hipStream_t stream) {
  const float* x = (const float*)d_in[0];
  const float* lw = (const float*)d_in[1];
  const float* lb = (const float*)d_in[2];
  const float* w2a_w = (const float*)d_in[3];
  const float* w2a_b = (const float*)d_in[4];
  const float* w2b_w = (const float*)d_in[5];
  const float* w2b_b = (const float*)d_in[6];
  float* out = (float*)d_out;

  if (ws_size >= WS_NEEDED) {
    char* ws = (char*)d_ws;
    unsigned short* Wf = (unsigned short*)(ws);
    float* bias = (float*)(ws + 81920);
    prep_fast<<<64, 256, 0, stream>>>(lw, lb, w2a_w, w2a_b, w2b_w, w2b_b, Wf, bias);
    stage2<<<2048, 256, 0, stream>>>(x, Wf, bias, out);
  } else {
    float* ws = (float*)d_ws;
    float* Mt = ws;
    float* bias2 = ws + 4096;
    float* Wt = ws + 4096 + 64;
    prep_kernel<<<1, 256, 0, stream>>>(lw, w2a_w, w2a_b, w2b_w, w2b_b, Mt, bias2, Wt);
    dim3 grid(NW / TW, NH, NB);
    volterra_main<<<grid, 256, 0, stream>>>(x, lb, Mt, bias2, Wt, out);
  }
}